// Round 4
// baseline (906.920 us; speedup 1.0000x reference)
//
#include <hip/hip_runtime.h>
#include <hip/hip_bf16.h>
#include <stdint.h>

// ---------------------------------------------------------------------------
// ConvAttention (B=2,S=4096,HID=1024,H=16,HD=64; conv k=(4,1) stride=(4,1))
// inputs f32, outputs f32; internal compute bf16 (verified round 3,
// absmax 0.0625 vs threshold 0.264).
// Round-4 fusions:
//  - dwconv folded into K/V GEMM epilogue (lane holds rows 4sk..4sk+3 = taps)
//  - logits+softmax+PV fused (logits written once, never re-read from HBM)
// Pipeline:
//   0. q f32 -> Xb bf16
//   1. convT: W* f32 [K][N] -> bf16 [N][K]
//   2a. Qh = Xb @ Wq (head-major bf16 [bh][4096][64])
//   2b. Kc,Vc = conv(Xb @ {Wk,Wv}) [bh][1024][64]   (conv in epilogue)
//   3. transpose Vc -> Vct [bh][64][1024]
//   4. fused: logits = Qh@Kc^T*exp(-lt) -> f32 out1; softmax; P@Vc -> oattn
//   5. out0 = oattn @ Wlin (f32)
// ---------------------------------------------------------------------------

using short8 = __attribute__((ext_vector_type(8))) short;
using f32x4  = __attribute__((ext_vector_type(4))) float;

__device__ __forceinline__ float bf2f(short u) {
  union { float f; uint32_t i; } v; v.i = ((uint32_t)(uint16_t)u) << 16; return v.f;
}
__device__ __forceinline__ short f2bf(float f) {
  union { float f; uint32_t i; } v; v.f = f;
  uint32_t r = v.i + 0x7FFFu + ((v.i >> 16) & 1u);   // RNE
  return (short)(uint16_t)(r >> 16);
}

__device__ __forceinline__ void async16(const void* g, void* l) {
  __builtin_amdgcn_global_load_lds(
      (const __attribute__((address_space(1))) void*)g,
      (__attribute__((address_space(3))) void*)l, 16, 0, 0);
}

// ---------------------------------------------------------------------------
__global__ void cvt8(const float* __restrict__ in, short* __restrict__ out) {
  const size_t i = ((size_t)blockIdx.x * 256 + threadIdx.x) * 8;
  float4 a = *(const float4*)(in + i);
  float4 b = *(const float4*)(in + i + 4);
  short8 o;
  o[0] = f2bf(a.x); o[1] = f2bf(a.y); o[2] = f2bf(a.z); o[3] = f2bf(a.w);
  o[4] = f2bf(b.x); o[5] = f2bf(b.y); o[6] = f2bf(b.z); o[7] = f2bf(b.w);
  *(short8*)(out + i) = o;
}

// ---------------------------------------------------------------------------
__global__ void convT(const float* __restrict__ in, short* __restrict__ out,
                      int R, int C) {
  __shared__ float tile[64][65];
  const int c0 = blockIdx.x * 64, r0 = blockIdx.y * 64;
  const int tx = threadIdx.x & 63, ty = threadIdx.x >> 6;
  #pragma unroll
  for (int i = ty; i < 64; i += 4)
    tile[i][tx] = in[(size_t)(r0 + i) * C + c0 + tx];
  __syncthreads();
  #pragma unroll
  for (int i = ty; i < 64; i += 4)
    out[(size_t)(c0 + i) * R + r0 + tx] = f2bf(tile[tx][i]);
}

// ---------------------------------------------------------------------------
__global__ void transpose2d(const short* __restrict__ in, short* __restrict__ out,
                            int R, int C) {
  __shared__ short tile[64][65];
  const size_t zoff = (size_t)blockIdx.z * (size_t)R * (size_t)C;
  const int c0 = blockIdx.x * 64, r0 = blockIdx.y * 64;
  const int tx = threadIdx.x & 63, ty = threadIdx.x >> 6;
  #pragma unroll
  for (int i = ty; i < 64; i += 4)
    tile[i][tx] = in[zoff + (size_t)(r0 + i) * C + c0 + tx];
  __syncthreads();
  #pragma unroll
  for (int i = ty; i < 64; i += 4)
    out[zoff + (size_t)(c0 + i) * R + r0 + tx] = tile[tx][i];
}

// ---------------------------------------------------------------------------
// C = A[M][K] * Bt[N][K]^T, bf16 inputs, f32 accum. 128x128 tile, BK=64.
// mode 0: f32 row-major -> Cf
// mode 1: bf16 head-major -> C   (off = (b*16+h)*262144 + s*64 + d)
// mode 2: depthwise-conv epilogue -> (z? C2 : C)[bh][1024][64]
struct GemmArgs {
  const short* A; const short* Bt;
  short* C; short* C2; float* Cf;
  long sA, sB, sC;
  long zA, zB, zC;
  int  K;
  const float* ltemp;       // mode 0: scale by exp(-ltemp[0]) if nonnull
  const float* cw;          // mode 2: conv weights [16][4]
  int  mode;
};

__global__ __launch_bounds__(256, 2)
void gemm_bt(GemmArgs g) {
  const int tid  = threadIdx.x;
  const int wave = tid >> 6, lane = tid & 63;
  const int l16 = lane & 15, l4 = lane >> 4;
  const int wm = wave & 1, wn = wave >> 1;
  const int m0 = blockIdx.y * 128, n0 = blockIdx.x * 128;
  const size_t zA = (size_t)blockIdx.z * g.zA;
  const size_t zB = (size_t)blockIdx.z * g.zB;
  const size_t zC = (size_t)blockIdx.z * g.zC;

  __shared__ __align__(16) short As[128 * 64];
  __shared__ __align__(16) short Bs[128 * 64];

  f32x4 acc[4][4] = {};

  const int srow = tid >> 3;
  const int scol = (tid & 7) << 3;
  const short* Abase = g.A + zA + (size_t)m0 * g.sA + scol;
  const short* Bbase = g.Bt + zB + (size_t)n0 * g.sB + scol;

  for (int k0 = 0; k0 < g.K; k0 += 64) {
    __syncthreads();
    #pragma unroll
    for (int c = 0; c < 4; ++c) {
      async16(Abase + (size_t)(c * 32 + srow) * g.sA + k0, &As[c * 2048 + wave * 512]);
      async16(Bbase + (size_t)(c * 32 + srow) * g.sB + k0, &Bs[c * 2048 + wave * 512]);
    }
    asm volatile("s_waitcnt vmcnt(0)" ::: "memory");
    __syncthreads();
    #pragma unroll
    for (int kk = 0; kk < 2; ++kk) {
      short8 a[4], b[4];
      #pragma unroll
      for (int t = 0; t < 4; ++t) {
        a[t] = *(const short8*)&As[(wm * 64 + t * 16 + l16) * 64 + kk * 32 + l4 * 8];
        b[t] = *(const short8*)&Bs[(wn * 64 + t * 16 + l16) * 64 + kk * 32 + l4 * 8];
      }
      #pragma unroll
      for (int i = 0; i < 4; ++i)
        #pragma unroll
        for (int j = 0; j < 4; ++j)
          acc[i][j] = __builtin_amdgcn_mfma_f32_16x16x32_bf16(a[i], b[j], acc[i][j], 0, 0, 0);
    }
  }

  if (g.mode == 0) {
    float sc = 1.0f;
    if (g.ltemp) sc = __expf(-g.ltemp[0]);
    float* Cz = g.Cf + zC;
    #pragma unroll
    for (int i = 0; i < 4; ++i) {
      const int row = m0 + wm * 64 + i * 16 + l4 * 4;
      #pragma unroll
      for (int j = 0; j < 4; ++j) {
        const int col = n0 + wn * 64 + j * 16 + l16;
        #pragma unroll
        for (int rr = 0; rr < 4; ++rr)
          Cz[(size_t)(row + rr) * g.sC + col] = acc[i][j][rr] * sc;
      }
    }
  } else if (g.mode == 1) {
    short* Cz = g.C + zC;
    #pragma unroll
    for (int i = 0; i < 4; ++i) {
      const int row = m0 + wm * 64 + i * 16 + l4 * 4;
      #pragma unroll
      for (int j = 0; j < 4; ++j) {
        const int col = n0 + wn * 64 + j * 16 + l16;
        const int hh = col >> 6, dd = col & 63;
        #pragma unroll
        for (int rr = 0; rr < 4; ++rr) {
          const int m = row + rr;
          const size_t off = (size_t)((m >> 12) * 16 + hh) * 262144
                           + (size_t)(m & 4095) * 64 + dd;
          Cz[off] = f2bf(acc[i][j][rr]);
        }
      }
    }
  } else {
    // mode 2: depthwise conv. lane holds rows row_base..row_base+3 (taps),
    // row_base = m0+wm*64+i*16+l4*4 (mod-4 aligned). h uniform per wave.
    const int h = (n0 + wn * 64) >> 6;
    float wv[4];
    #pragma unroll
    for (int t = 0; t < 4; ++t) wv[t] = g.cw[h * 4 + t];
    short* dst = blockIdx.z ? g.C2 : g.C;
    #pragma unroll
    for (int i = 0; i < 4; ++i) {
      const int row_base = m0 + wm * 64 + i * 16 + l4 * 4;
      const int b  = row_base >> 12;
      const int sk = (row_base & 4095) >> 2;
      #pragma unroll
      for (int j = 0; j < 4; ++j) {
        const int d = j * 16 + l16;
        float v = wv[0] * acc[i][j][0] + wv[1] * acc[i][j][1]
                + wv[2] * acc[i][j][2] + wv[3] * acc[i][j][3];
        dst[(size_t)(b * 16 + h) * 65536 + (size_t)sk * 64 + d] = f2bf(v);
      }
    }
  }
}

// ---------------------------------------------------------------------------
// fused logits + softmax + PV. block = 256 (4 waves), grid (128 q-tiles, 32 bh).
// wave w computes S cols [w*256, w*256+256); acc[2][16] f32x4 = 128 VGPR.
__global__ __launch_bounds__(256, 2)
void fused_attn(const short* __restrict__ qh, const short* __restrict__ kc,
                const short* __restrict__ vct, const float* __restrict__ lt,
                float* __restrict__ logits, short* __restrict__ oattn) {
  const int bh = blockIdx.y, q0 = blockIdx.x * 32;
  const int tid = threadIdx.x;
  const int wave = tid >> 6, lane = tid & 63;
  const int l16 = lane & 15, l4 = lane >> 4;

  __shared__ __align__(16) short att[32 * 1024];   // XOR-swizzled rows
  __shared__ float redm[32][4], reds[32][4];
  __shared__ float rowmax[32], rowsum[32];

  const float sc = __expf(-lt[0]);

  // ---- QK^T ----
  const short* qbase = qh + (size_t)bh * 262144 + (size_t)q0 * 64;
  const short* kbase = kc + (size_t)bh * 65536 + (size_t)(wave * 256) * 64;

  short8 a[2][2];
  #pragma unroll
  for (int i = 0; i < 2; ++i)
    #pragma unroll
    for (int kk = 0; kk < 2; ++kk)
      a[i][kk] = *(const short8*)(qbase + (size_t)(i * 16 + l16) * 64 + kk * 32 + l4 * 8);

  f32x4 acc[2][16];
  #pragma unroll
  for (int i = 0; i < 2; ++i)
    #pragma unroll
    for (int j = 0; j < 16; ++j)
      acc[i][j] = f32x4{0.f, 0.f, 0.f, 0.f};

  #pragma unroll 4
  for (int j = 0; j < 16; ++j) {
    short8 b0 = *(const short8*)(kbase + (size_t)(j * 16 + l16) * 64 + l4 * 8);
    short8 b1 = *(const short8*)(kbase + (size_t)(j * 16 + l16) * 64 + 32 + l4 * 8);
    acc[0][j] = __builtin_amdgcn_mfma_f32_16x16x32_bf16(a[0][0], b0, acc[0][j], 0, 0, 0);
    acc[0][j] = __builtin_amdgcn_mfma_f32_16x16x32_bf16(a[0][1], b1, acc[0][j], 0, 0, 0);
    acc[1][j] = __builtin_amdgcn_mfma_f32_16x16x32_bf16(a[1][0], b0, acc[1][j], 0, 0, 0);
    acc[1][j] = __builtin_amdgcn_mfma_f32_16x16x32_bf16(a[1][1], b1, acc[1][j], 0, 0, 0);
  }

  // ---- scale, write f32 logits, per-lane row max ----
  float* lgbase = logits + (size_t)bh * 4194304 + (size_t)q0 * 1024 + wave * 256;
  float pmax[2][4];
  #pragma unroll
  for (int i = 0; i < 2; ++i)
    #pragma unroll
    for (int rr = 0; rr < 4; ++rr) pmax[i][rr] = -3.4e38f;

  #pragma unroll
  for (int i = 0; i < 2; ++i)
    #pragma unroll
    for (int j = 0; j < 16; ++j)
      #pragma unroll
      for (int rr = 0; rr < 4; ++rr) {
        float v = acc[i][j][rr] * sc;
        acc[i][j][rr] = v;
        lgbase[(size_t)(i * 16 + l4 * 4 + rr) * 1024 + j * 16 + l16] = v;
        pmax[i][rr] = fmaxf(pmax[i][rr], v);
      }

  // reduce max over the 16 l16-lanes (same l4 group)
  #pragma unroll
  for (int i = 0; i < 2; ++i)
    #pragma unroll
    for (int rr = 0; rr < 4; ++rr) {
      float m = pmax[i][rr];
      #pragma unroll
      for (int d = 1; d < 16; d <<= 1) m = fmaxf(m, __shfl_xor(m, d, 64));
      pmax[i][rr] = m;
    }
  if (l16 == 0) {
    #pragma unroll
    for (int i = 0; i < 2; ++i)
      #pragma unroll
      for (int rr = 0; rr < 4; ++rr)
        redm[i * 16 + l4 * 4 + rr][wave] = pmax[i][rr];
  }
  __syncthreads();
  if (tid < 32)
    rowmax[tid] = fmaxf(fmaxf(redm[tid][0], redm[tid][1]),
                        fmaxf(redm[tid][2], redm[tid][3]));
  __syncthreads();

  // ---- exp from registers -> att LDS (bf16, XOR swizzle), row sums ----
  float psum[2][4] = {};
  #pragma unroll
  for (int i = 0; i < 2; ++i)
    #pragma unroll
    for (int rr = 0; rr < 4; ++rr) {
      const int row = i * 16 + l4 * 4 + rr;
      const float rm = rowmax[row];
      const int sw = (row & 7) << 3;
      #pragma unroll
      for (int j = 0; j < 16; ++j) {
        float e = __expf(acc[i][j][rr] - rm);
        psum[i][rr] += e;
        const int col = wave * 256 + j * 16 + l16;
        att[row * 1024 + (col ^ sw)] = f2bf(e);
      }
    }
  #pragma unroll
  for (int i = 0; i < 2; ++i)
    #pragma unroll
    for (int rr = 0; rr < 4; ++rr) {
      float s = psum[i][rr];
      #pragma unroll
      for (int d = 1; d < 16; d <<= 1) s += __shfl_xor(s, d, 64);
      psum[i][rr] = s;
    }
  if (l16 == 0) {
    #pragma unroll
    for (int i = 0; i < 2; ++i)
      #pragma unroll
      for (int rr = 0; rr < 4; ++rr)
        reds[i * 16 + l4 * 4 + rr][wave] = psum[i][rr];
  }
  __syncthreads();
  if (tid < 32)
    rowsum[tid] = reds[tid][0] + reds[tid][1] + reds[tid][2] + reds[tid][3];
  __syncthreads();

  // ---- PV: out[32][64] = att @ Vct^T ----
  const int mt = wave & 1;
  const int n0 = (wave >> 1) * 32;
  const short* vb = vct + (size_t)bh * 65536;
  f32x4 o0 = {}, o1 = {};
  const int arow = mt * 16 + l16;
  const int asw  = (arow & 7) << 3;
  #pragma unroll 4
  for (int kk = 0; kk < 32; ++kk) {
    const int cb = kk * 32 + l4 * 8;
    short8 pa = *(const short8*)&att[arow * 1024 + (cb ^ asw)];
    short8 b0 = *(const short8*)(vb + (size_t)(n0 + l16) * 1024 + cb);
    short8 b1 = *(const short8*)(vb + (size_t)(n0 + 16 + l16) * 1024 + cb);
    o0 = __builtin_amdgcn_mfma_f32_16x16x32_bf16(pa, b0, o0, 0, 0, 0);
    o1 = __builtin_amdgcn_mfma_f32_16x16x32_bf16(pa, b1, o1, 0, 0, 0);
  }
  short* op = oattn + ((size_t)(bh >> 4) * 4096 + q0) * 1024 + (bh & 15) * 64;
  #pragma unroll
  for (int rr = 0; rr < 4; ++rr) {
    const int row = mt * 16 + l4 * 4 + rr;
    const float inv = 1.0f / rowsum[row];
    op[(size_t)row * 1024 + n0 + l16]      = f2bf(o0[rr] * inv);
    op[(size_t)row * 1024 + n0 + 16 + l16] = f2bf(o1[rr] * inv);
  }
}

// ---------------------------------------------------------------------------
extern "C" void kernel_launch(void* const* d_in, const int* in_sizes, int n_in,
                              void* d_out, int out_size, void* d_ws, size_t ws_size,
                              hipStream_t stream) {
  const float* q    = (const float*)d_in[0];
  const float* Wq   = (const float*)d_in[1];
  const float* Wk   = (const float*)d_in[2];
  const float* Wv   = (const float*)d_in[3];
  const float* Wlin = (const float*)d_in[4];
  const float* cw   = (const float*)d_in[5];
  const float* lt   = (const float*)d_in[6];

  float* out_f    = (float*)d_out;             // output 0: [8192][1024] f32
  float* logits_f = out_f + 8388608;           // output 1: [32][4096][1024] f32

  short* ws    = (short*)d_ws;
  short* Wt    = ws;                 // 4 x 1048576
  short* Xb    = ws + 4194304;       // 8388608 ; reused as oattn
  short* QKVq  = ws + 12582912;      // 8388608 head-major Q
  short* Kc    = ws + 20971520;      // [32][1024][64]
  short* Vc    = ws + 23068672;      // [32][1024][64]
  short* Vct   = ws + 25165824;      // [32][64][1024]
  short* oattn = Xb;
  // total 27,262,976 shorts = 54.5 MB

  cvt8<<<dim3(4096), 256, 0, stream>>>(q, Xb);

  convT<<<dim3(16, 16), 256, 0, stream>>>(Wq,   Wt,           1024, 1024);
  convT<<<dim3(16, 16), 256, 0, stream>>>(Wk,   Wt + 1048576, 1024, 1024);
  convT<<<dim3(16, 16), 256, 0, stream>>>(Wv,   Wt + 2097152, 1024, 1024);
  convT<<<dim3(16, 16), 256, 0, stream>>>(Wlin, Wt + 3145728, 1024, 1024);

  // Q projection (head-major epilogue)
  GemmArgs gq = {};
  gq.A = Xb; gq.Bt = Wt; gq.C = QKVq;
  gq.sA = 1024; gq.sB = 1024; gq.sC = 0;
  gq.zA = 0; gq.zB = 0; gq.zC = 0;
  gq.K = 1024; gq.mode = 1;
  gemm_bt<<<dim3(8, 64, 1), 256, 0, stream>>>(gq);

  // K,V projections with fused depthwise conv (z=0 -> Kc, z=1 -> Vc)
  GemmArgs gkv = {};
  gkv.A = Xb; gkv.Bt = Wt + 1048576; gkv.C = Kc; gkv.C2 = Vc;
  gkv.sA = 1024; gkv.sB = 1024; gkv.sC = 0;
  gkv.zA = 0; gkv.zB = 1048576; gkv.zC = 0;
  gkv.K = 1024; gkv.cw = cw; gkv.mode = 2;
  gemm_bt<<<dim3(8, 64, 2), 256, 0, stream>>>(gkv);

  // Vc -> Vct
  transpose2d<<<dim3(1, 16, 32), 256, 0, stream>>>(Vc, Vct, 1024, 64);

  // fused logits (f32 out) + softmax + PV
  fused_attn<<<dim3(128, 32), 256, 0, stream>>>(QKVq, Kc, Vct, lt, logits_f, oattn);

  // out = oattn @ Wlin
  GemmArgs gf = {};
  gf.A = oattn; gf.Bt = Wt + 3145728; gf.Cf = out_f;
  gf.sA = 1024; gf.sB = 1024; gf.sC = 1024;
  gf.zA = 0; gf.zB = 0; gf.zC = 0;
  gf.K = 1024; gf.mode = 0;
  gemm_bt<<<dim3(8, 64, 1), 256, 0, stream>>>(gf);
}

// Round 5
// 421.513 us; speedup vs baseline: 2.1516x; 2.1516x over previous
//
#include <hip/hip_runtime.h>
#include <hip/hip_bf16.h>
#include <stdint.h>

// ---------------------------------------------------------------------------
// ConvAttention (B=2,S=4096,HID=1024,H=16,HD=64; conv k=(4,1) stride=(4,1))
// inputs f32, outputs f32; internal compute bf16 (round 3: absmax 0.0625).
// Round-5 fix: round-4's fused_attn spilled acc[2][16] to scratch
// (#pragma unroll 4 + runtime-indexed ext_vector array, rule #20) ->
// 2 GB scratch traffic, 763 us. Restructured: consume each QK^T col-tile
// immediately (scalar f32x4 accs), raw bf16 logits parked in swizzled LDS,
// exp applied in a second LDS pass. No big register array, no spill.
// Pipeline:
//   0. q f32 -> Xb bf16
//   1. convT: W* f32 [K][N] -> bf16 [N][K]
//   2a. Qh = Xb @ Wq (head-major bf16 [bh][4096][64])
//   2b. Kc,Vc = conv(Xb @ {Wk,Wv}) [bh][1024][64]   (conv in epilogue)
//   3. transpose Vc -> Vct [bh][64][1024]
//   4. fused: logits f32 -> out1; softmax (LDS); P@Vc -> oattn
//   5. out0 = oattn @ Wlin (f32)
// ---------------------------------------------------------------------------

using short8 = __attribute__((ext_vector_type(8))) short;
using f32x4  = __attribute__((ext_vector_type(4))) float;

__device__ __forceinline__ float bf2f(short u) {
  union { float f; uint32_t i; } v; v.i = ((uint32_t)(uint16_t)u) << 16; return v.f;
}
__device__ __forceinline__ short f2bf(float f) {
  union { float f; uint32_t i; } v; v.f = f;
  uint32_t r = v.i + 0x7FFFu + ((v.i >> 16) & 1u);   // RNE
  return (short)(uint16_t)(r >> 16);
}

__device__ __forceinline__ void async16(const void* g, void* l) {
  __builtin_amdgcn_global_load_lds(
      (const __attribute__((address_space(1))) void*)g,
      (__attribute__((address_space(3))) void*)l, 16, 0, 0);
}

// ---------------------------------------------------------------------------
__global__ void cvt8(const float* __restrict__ in, short* __restrict__ out) {
  const size_t i = ((size_t)blockIdx.x * 256 + threadIdx.x) * 8;
  float4 a = *(const float4*)(in + i);
  float4 b = *(const float4*)(in + i + 4);
  short8 o;
  o[0] = f2bf(a.x); o[1] = f2bf(a.y); o[2] = f2bf(a.z); o[3] = f2bf(a.w);
  o[4] = f2bf(b.x); o[5] = f2bf(b.y); o[6] = f2bf(b.z); o[7] = f2bf(b.w);
  *(short8*)(out + i) = o;
}

// ---------------------------------------------------------------------------
__global__ void convT(const float* __restrict__ in, short* __restrict__ out,
                      int R, int C) {
  __shared__ float tile[64][65];
  const int c0 = blockIdx.x * 64, r0 = blockIdx.y * 64;
  const int tx = threadIdx.x & 63, ty = threadIdx.x >> 6;
  #pragma unroll
  for (int i = ty; i < 64; i += 4)
    tile[i][tx] = in[(size_t)(r0 + i) * C + c0 + tx];
  __syncthreads();
  #pragma unroll
  for (int i = ty; i < 64; i += 4)
    out[(size_t)(c0 + i) * R + r0 + tx] = f2bf(tile[tx][i]);
}

// ---------------------------------------------------------------------------
__global__ void transpose2d(const short* __restrict__ in, short* __restrict__ out,
                            int R, int C) {
  __shared__ short tile[64][65];
  const size_t zoff = (size_t)blockIdx.z * (size_t)R * (size_t)C;
  const int c0 = blockIdx.x * 64, r0 = blockIdx.y * 64;
  const int tx = threadIdx.x & 63, ty = threadIdx.x >> 6;
  #pragma unroll
  for (int i = ty; i < 64; i += 4)
    tile[i][tx] = in[zoff + (size_t)(r0 + i) * C + c0 + tx];
  __syncthreads();
  #pragma unroll
  for (int i = ty; i < 64; i += 4)
    out[zoff + (size_t)(c0 + i) * R + r0 + tx] = tile[tx][i];
}

// ---------------------------------------------------------------------------
// C = A[M][K] * Bt[N][K]^T, bf16 inputs, f32 accum. 128x128 tile, BK=64.
// mode 0: f32 row-major -> Cf
// mode 1: bf16 head-major -> C
// mode 2: depthwise-conv epilogue -> (z? C2 : C)[bh][1024][64]
struct GemmArgs {
  const short* A; const short* Bt;
  short* C; short* C2; float* Cf;
  long sA, sB, sC;
  long zA, zB, zC;
  int  K;
  const float* ltemp;
  const float* cw;
  int  mode;
};

__global__ __launch_bounds__(256, 2)
void gemm_bt(GemmArgs g) {
  const int tid  = threadIdx.x;
  const int wave = tid >> 6, lane = tid & 63;
  const int l16 = lane & 15, l4 = lane >> 4;
  const int wm = wave & 1, wn = wave >> 1;
  const int m0 = blockIdx.y * 128, n0 = blockIdx.x * 128;
  const size_t zA = (size_t)blockIdx.z * g.zA;
  const size_t zB = (size_t)blockIdx.z * g.zB;
  const size_t zC = (size_t)blockIdx.z * g.zC;

  __shared__ __align__(16) short As[128 * 64];
  __shared__ __align__(16) short Bs[128 * 64];

  f32x4 acc[4][4] = {};

  const int srow = tid >> 3;
  const int scol = (tid & 7) << 3;
  const short* Abase = g.A + zA + (size_t)m0 * g.sA + scol;
  const short* Bbase = g.Bt + zB + (size_t)n0 * g.sB + scol;

  for (int k0 = 0; k0 < g.K; k0 += 64) {
    __syncthreads();
    #pragma unroll
    for (int c = 0; c < 4; ++c) {
      async16(Abase + (size_t)(c * 32 + srow) * g.sA + k0, &As[c * 2048 + wave * 512]);
      async16(Bbase + (size_t)(c * 32 + srow) * g.sB + k0, &Bs[c * 2048 + wave * 512]);
    }
    asm volatile("s_waitcnt vmcnt(0)" ::: "memory");
    __syncthreads();
    #pragma unroll
    for (int kk = 0; kk < 2; ++kk) {
      short8 a[4], b[4];
      #pragma unroll
      for (int t = 0; t < 4; ++t) {
        a[t] = *(const short8*)&As[(wm * 64 + t * 16 + l16) * 64 + kk * 32 + l4 * 8];
        b[t] = *(const short8*)&Bs[(wn * 64 + t * 16 + l16) * 64 + kk * 32 + l4 * 8];
      }
      #pragma unroll
      for (int i = 0; i < 4; ++i)
        #pragma unroll
        for (int j = 0; j < 4; ++j)
          acc[i][j] = __builtin_amdgcn_mfma_f32_16x16x32_bf16(a[i], b[j], acc[i][j], 0, 0, 0);
    }
  }

  if (g.mode == 0) {
    float sc = 1.0f;
    if (g.ltemp) sc = __expf(-g.ltemp[0]);
    float* Cz = g.Cf + zC;
    #pragma unroll
    for (int i = 0; i < 4; ++i) {
      const int row = m0 + wm * 64 + i * 16 + l4 * 4;
      #pragma unroll
      for (int j = 0; j < 4; ++j) {
        const int col = n0 + wn * 64 + j * 16 + l16;
        #pragma unroll
        for (int rr = 0; rr < 4; ++rr)
          Cz[(size_t)(row + rr) * g.sC + col] = acc[i][j][rr] * sc;
      }
    }
  } else if (g.mode == 1) {
    short* Cz = g.C + zC;
    #pragma unroll
    for (int i = 0; i < 4; ++i) {
      const int row = m0 + wm * 64 + i * 16 + l4 * 4;
      #pragma unroll
      for (int j = 0; j < 4; ++j) {
        const int col = n0 + wn * 64 + j * 16 + l16;
        const int hh = col >> 6, dd = col & 63;
        #pragma unroll
        for (int rr = 0; rr < 4; ++rr) {
          const int m = row + rr;
          const size_t off = (size_t)((m >> 12) * 16 + hh) * 262144
                           + (size_t)(m & 4095) * 64 + dd;
          Cz[off] = f2bf(acc[i][j][rr]);
        }
      }
    }
  } else {
    const int h = (n0 + wn * 64) >> 6;
    float wv[4];
    #pragma unroll
    for (int t = 0; t < 4; ++t) wv[t] = g.cw[h * 4 + t];
    short* dst = blockIdx.z ? g.C2 : g.C;
    #pragma unroll
    for (int i = 0; i < 4; ++i) {
      const int row_base = m0 + wm * 64 + i * 16 + l4 * 4;
      const int b  = row_base >> 12;
      const int sk = (row_base & 4095) >> 2;
      #pragma unroll
      for (int j = 0; j < 4; ++j) {
        const int d = j * 16 + l16;
        float v = wv[0] * acc[i][j][0] + wv[1] * acc[i][j][1]
                + wv[2] * acc[i][j][2] + wv[3] * acc[i][j][3];
        dst[(size_t)(b * 16 + h) * 65536 + (size_t)sk * 64 + d] = f2bf(v);
      }
    }
  }
}

// ---------------------------------------------------------------------------
// fused logits + softmax + PV, spill-free.
// block = 256 (4 waves), grid (128 q-tiles, 32 bh). wave w: S-cols [w*256,+256).
// Phase 1: per col-tile j: 4 MFMA -> scalar accs -> scale -> f32 logits store
//          -> pmax -> bf16 raw logit into swizzled LDS. accs die each j.
// Phase 2: rowmax reduce (shfl + LDS), exp in-place over LDS, rowsum.
// Phase 3: PV from LDS + Vct, scale by 1/rowsum, bf16 head-major out.
__global__ __launch_bounds__(256, 2)
void fused_attn(const short* __restrict__ qh, const short* __restrict__ kc,
                const short* __restrict__ vct, const float* __restrict__ lt,
                float* __restrict__ logits, short* __restrict__ oattn) {
  const int bh = blockIdx.y, q0 = blockIdx.x * 32;
  const int tid = threadIdx.x;
  const int wave = tid >> 6, lane = tid & 63;
  const int l16 = lane & 15, l4 = lane >> 4;

  __shared__ __align__(16) short att[32 * 1024];   // XOR-swizzled rows
  __shared__ float redm[32][4], reds[32][8];
  __shared__ float rowmax[32], rowsum[32];

  const float sc = __expf(-lt[0]);

  const short* qbase = qh + (size_t)bh * 262144 + (size_t)q0 * 64;
  const short* kbase = kc + (size_t)bh * 65536 + (size_t)(wave * 256) * 64;
  float* lgbase = logits + (size_t)bh * 4194304 + (size_t)q0 * 1024 + wave * 256;

  short8 a[2][2];
  #pragma unroll
  for (int i = 0; i < 2; ++i)
    #pragma unroll
    for (int kk = 0; kk < 2; ++kk)
      a[i][kk] = *(const short8*)(qbase + (size_t)(i * 16 + l16) * 64 + kk * 32 + l4 * 8);

  float pmax[2][4];
  #pragma unroll
  for (int i = 0; i < 2; ++i)
    #pragma unroll
    for (int rr = 0; rr < 4; ++rr) pmax[i][rr] = -3.4e38f;

  // ---- phase 1: QK^T col-tiles, consumed immediately ----
  #pragma unroll 4
  for (int j = 0; j < 16; ++j) {
    short8 b0 = *(const short8*)(kbase + (size_t)(j * 16 + l16) * 64 + l4 * 8);
    short8 b1 = *(const short8*)(kbase + (size_t)(j * 16 + l16) * 64 + 32 + l4 * 8);
    f32x4 acc[2];
    #pragma unroll
    for (int i = 0; i < 2; ++i) {
      acc[i] = f32x4{0.f, 0.f, 0.f, 0.f};
      acc[i] = __builtin_amdgcn_mfma_f32_16x16x32_bf16(a[i][0], b0, acc[i], 0, 0, 0);
      acc[i] = __builtin_amdgcn_mfma_f32_16x16x32_bf16(a[i][1], b1, acc[i], 0, 0, 0);
    }
    const int colg = wave * 256 + j * 16 + l16;
    #pragma unroll
    for (int i = 0; i < 2; ++i)
      #pragma unroll
      for (int rr = 0; rr < 4; ++rr) {
        const int row = i * 16 + l4 * 4 + rr;
        float v = acc[i][rr] * sc;
        lgbase[(size_t)row * 1024 + j * 16 + l16] = v;
        pmax[i][rr] = fmaxf(pmax[i][rr], v);
        att[row * 1024 + (colg ^ ((row & 7) << 3))] = f2bf(v);
      }
  }

  // ---- phase 2a: rowmax (16-lane shfl groups share l4 -> 4 rows) ----
  #pragma unroll
  for (int i = 0; i < 2; ++i)
    #pragma unroll
    for (int rr = 0; rr < 4; ++rr) {
      float m = pmax[i][rr];
      #pragma unroll
      for (int d = 1; d < 16; d <<= 1) m = fmaxf(m, __shfl_xor(m, d, 64));
      pmax[i][rr] = m;
    }
  if (l16 == 0) {
    #pragma unroll
    for (int i = 0; i < 2; ++i)
      #pragma unroll
      for (int rr = 0; rr < 4; ++rr)
        redm[i * 16 + l4 * 4 + rr][wave] = pmax[i][rr];
  }
  __syncthreads();
  if (tid < 32)
    rowmax[tid] = fmaxf(fmaxf(redm[tid][0], redm[tid][1]),
                        fmaxf(redm[tid][2], redm[tid][3]));
  __syncthreads();

  // ---- phase 2b: exp in place over LDS, row sums ----
  const int er = tid >> 3, eseg = tid & 7;        // 8 threads/row, 128 cols each
  const float erm = rowmax[er];
  const int esw = (er & 7) << 3;
  float es = 0.f;
  #pragma unroll
  for (int u = 0; u < 16; ++u) {
    const int base = er * 1024 + ((eseg * 128 + u * 8) ^ esw);
    short8 x = *(const short8*)&att[base];
    short8 o;
    #pragma unroll
    for (int e = 0; e < 8; ++e) {
      float ev = __expf(bf2f(x[e]) - erm);
      es += ev;
      o[e] = f2bf(ev);
    }
    *(short8*)&att[base] = o;
  }
  reds[er][eseg] = es;
  __syncthreads();
  if (tid < 32) {
    float s = 0.f;
    #pragma unroll
    for (int i = 0; i < 8; ++i) s += reds[tid][i];
    rowsum[tid] = s;
  }
  __syncthreads();

  // ---- phase 3: PV ----
  const int mt = wave & 1;
  const int n0 = (wave >> 1) * 32;
  const short* vb = vct + (size_t)bh * 65536;
  f32x4 o0 = {}, o1 = {};
  const int arow = mt * 16 + l16;
  const int asw  = (arow & 7) << 3;
  #pragma unroll 4
  for (int kk = 0; kk < 32; ++kk) {
    const int cb = kk * 32 + l4 * 8;
    short8 pa = *(const short8*)&att[arow * 1024 + (cb ^ asw)];
    short8 b0 = *(const short8*)(vb + (size_t)(n0 + l16) * 1024 + cb);
    short8 b1 = *(const short8*)(vb + (size_t)(n0 + 16 + l16) * 1024 + cb);
    o0 = __builtin_amdgcn_mfma_f32_16x16x32_bf16(pa, b0, o0, 0, 0, 0);
    o1 = __builtin_amdgcn_mfma_f32_16x16x32_bf16(pa, b1, o1, 0, 0, 0);
  }
  short* op = oattn + ((size_t)(bh >> 4) * 4096 + q0) * 1024 + (bh & 15) * 64;
  #pragma unroll
  for (int rr = 0; rr < 4; ++rr) {
    const int row = mt * 16 + l4 * 4 + rr;
    const float inv = 1.0f / rowsum[row];
    op[(size_t)row * 1024 + n0 + l16]      = f2bf(o0[rr] * inv);
    op[(size_t)row * 1024 + n0 + 16 + l16] = f2bf(o1[rr] * inv);
  }
}

// ---------------------------------------------------------------------------
extern "C" void kernel_launch(void* const* d_in, const int* in_sizes, int n_in,
                              void* d_out, int out_size, void* d_ws, size_t ws_size,
                              hipStream_t stream) {
  const float* q    = (const float*)d_in[0];
  const float* Wq   = (const float*)d_in[1];
  const float* Wk   = (const float*)d_in[2];
  const float* Wv   = (const float*)d_in[3];
  const float* Wlin = (const float*)d_in[4];
  const float* cw   = (const float*)d_in[5];
  const float* lt   = (const float*)d_in[6];

  float* out_f    = (float*)d_out;             // output 0: [8192][1024] f32
  float* logits_f = out_f + 8388608;           // output 1: [32][4096][1024] f32

  short* ws    = (short*)d_ws;
  short* Wt    = ws;                 // 4 x 1048576
  short* Xb    = ws + 4194304;       // 8388608 ; reused as oattn
  short* QKVq  = ws + 12582912;      // 8388608 head-major Q
  short* Kc    = ws + 20971520;      // [32][1024][64]
  short* Vc    = ws + 23068672;      // [32][1024][64]
  short* Vct   = ws + 25165824;      // [32][64][1024]
  short* oattn = Xb;
  // total 27,262,976 shorts = 54.5 MB

  cvt8<<<dim3(4096), 256, 0, stream>>>(q, Xb);

  convT<<<dim3(16, 16), 256, 0, stream>>>(Wq,   Wt,           1024, 1024);
  convT<<<dim3(16, 16), 256, 0, stream>>>(Wk,   Wt + 1048576, 1024, 1024);
  convT<<<dim3(16, 16), 256, 0, stream>>>(Wv,   Wt + 2097152, 1024, 1024);
  convT<<<dim3(16, 16), 256, 0, stream>>>(Wlin, Wt + 3145728, 1024, 1024);

  // Q projection (head-major epilogue)
  GemmArgs gq = {};
  gq.A = Xb; gq.Bt = Wt; gq.C = QKVq;
  gq.sA = 1024; gq.sB = 1024; gq.sC = 0;
  gq.zA = 0; gq.zB = 0; gq.zC = 0;
  gq.K = 1024; gq.mode = 1;
  gemm_bt<<<dim3(8, 64, 1), 256, 0, stream>>>(gq);

  // K,V projections with fused depthwise conv (z=0 -> Kc, z=1 -> Vc)
  GemmArgs gkv = {};
  gkv.A = Xb; gkv.Bt = Wt + 1048576; gkv.C = Kc; gkv.C2 = Vc;
  gkv.sA = 1024; gkv.sB = 1024; gkv.sC = 0;
  gkv.zA = 0; gkv.zB = 1048576; gkv.zC = 0;
  gkv.K = 1024; gkv.cw = cw; gkv.mode = 2;
  gemm_bt<<<dim3(8, 64, 2), 256, 0, stream>>>(gkv);

  // Vc -> Vct
  transpose2d<<<dim3(1, 16, 32), 256, 0, stream>>>(Vc, Vct, 1024, 64);

  // fused logits (f32 out) + softmax + PV
  fused_attn<<<dim3(128, 32), 256, 0, stream>>>(QKVq, Kc, Vct, lt, logits_f, oattn);

  // out = oattn @ Wlin
  GemmArgs gf = {};
  gf.A = oattn; gf.Bt = Wt + 3145728; gf.Cf = out_f;
  gf.sA = 1024; gf.sB = 1024; gf.sC = 1024;
  gf.zA = 0; gf.zB = 0; gf.zC = 0;
  gf.K = 1024; gf.mode = 0;
  gemm_bt<<<dim3(8, 64, 1), 256, 0, stream>>>(gf);
}